// Round 17
// baseline (1007.653 us; speedup 1.0000x reference)
//
#include <hip/hip_runtime.h>

// DMMRLoss_52621939310662 — round 17: issue-slot surgery.
// r16: VALUBusy 54%, ~17k issue slots/thread of which 11.3k are irreducible
// FMA. Cuts: conv2 broadcast reads 4536 scalar -> 1296 ds_read_b128 (uniform
// addr, conflict-free); conv2 weights 216 uncoalesced scalar -> 54 coalesced
// dwordx4 via W2T4[(ic,td,th)][oc] pack; conv1 weights -> s_load via
// readfirstlane(wave); conv1-out writes 64 scalar -> 16 b128 (CS=552, ZS=68,
// bank-uniform). Staging keeps PS=433/RS=25 (4-way floor).

static constexpr int kPS = 433;    // staging plane stride (scalar reads, 4-way)
static constexpr int kRS = 25;     // staging row stride
static constexpr int kCS = 552;    // conv1-out channel stride (mult 4, 16B rows)
static constexpr int kZS = 68;     // conv1-out z stride (mult 4)
static constexpr int kHOff = 6912; // h[k] region after partials

// Whole-block per-patch pipeline. sBuf: 8832 floats. Returns (tanh*keep, keep)
// valid at t==0. WPACK: use packed W1T4/W2T4 from ws (fast path).
template <bool WPACK>
static __device__ __forceinline__ float2 dmr17_patch(
    int p, int t,
    const float* __restrict__ src, const float* __restrict__ tgt,
    const float* __restrict__ c1w, const float* __restrict__ c1b,
    const float* __restrict__ c2w, const float* __restrict__ c2b,
    const float* __restrict__ w2t4,
    const float* __restrict__ fw1, const float* __restrict__ f1b,
    const float* __restrict__ f2w, const float* __restrict__ f2b,
    float* __restrict__ sBuf, float* __restrict__ sRed) {
  int pd = p / 169; int rem = p - pd * 169; int phh = rem / 13; int pww = rem - phh * 13;
  int z0 = pd * 17, y0 = phh * 17, x0 = pww * 17;

  int wvu = __builtin_amdgcn_readfirstlane(t >> 6);  // wave id, provably scalar
  int od  = (t >> 3) & 7, oh = t & 7;
  int oc2 = t & 63;

  // ---- stage tgt patch + count zeros ----
  float cnt = 0.f;
  for (int idx = t; idx < 4913; idx += 256) {
    int a = idx / 289; int r2 = idx - a * 289; int b = r2 / 17; int c = r2 - b * 17;
    float v = tgt[((size_t)(z0 + a) * 222 + (y0 + b)) * 222 + (x0 + c)];
    sBuf[a * kPS + b * kRS + c] = v;
    if (v == 0.0f) cnt += 1.f;
  }
  sRed[t] = cnt;
  __syncthreads();
  for (int o = 128; o > 0; o >>= 1) {
    if (t < o) sRed[t] += sRed[t + o];
    __syncthreads();
  }
  float keep = (sRed[0] / 4913.0f <= 0.5f) ? 1.0f : 0.0f;
  __syncthreads();

  float acc2[27];
  #pragma unroll
  for (int i = 0; i < 27; i++) acc2[i] = 0.f;

  #pragma unroll 1
  for (int half = 0; half < 2; half++) {
    float acc[4][8];
    #pragma unroll
    for (int i = 0; i < 4; i++)
      #pragma unroll
      for (int j = 0; j < 8; j++) acc[i][j] = 0.f;

    #pragma unroll 1
    for (int ic = 0; ic < 2; ic++) {
      if (half + ic > 0) {            // restage: src (ic1) or tgt (half1/ic0)
        const float* vol = ic ? src : tgt;
        __syncthreads();
        for (int idx = t; idx < 4913; idx += 256) {
          int a = idx / 289; int r2 = idx - a * 289; int b = r2 / 17; int c = r2 - b * 17;
          sBuf[a * kPS + b * kRS + c] =
              vol[((size_t)(z0 + a) * 222 + (y0 + b)) * 222 + (x0 + c)];
        }
        __syncthreads();
      }
      #pragma unroll 1
      for (int td = 0; td < 3; td++) {
        #pragma unroll 1
        for (int th = 0; th < 3; th++) {
          int rbase = (2 * od + td) * kPS + (2 * oh + th) * kRS;
          float a[17];
          #pragma unroll
          for (int x = 0; x < 17; x++) a[x] = sBuf[rbase + x];
          #pragma unroll
          for (int ocr = 0; ocr < 4; ocr++) {
            int oc = half * 16 + wvu * 4 + ocr;      // scalar -> s_load weights
            const float* wp = c1w + oc * 54 + ic * 27 + td * 9 + th * 3;
            float w0 = wp[0], w1 = wp[1], w2 = wp[2];
            #pragma unroll
            for (int ow = 0; ow < 8; ow++)
              acc[ocr][ow] += a[2 * ow] * w0 + a[2 * ow + 1] * w1 + a[2 * ow + 2] * w2;
          }
        }
      }
    }
    __syncthreads();                  // conv1 reads of staged patch done
    #pragma unroll
    for (int ocr = 0; ocr < 4; ocr++) {
      int lo = wvu * 4 + ocr;
      float b = c1b[half * 16 + lo];
      int base = lo * kCS + od * kZS + oh * 8;       // mult-4 -> 16B aligned
      float4 v0, v1;
      v0.x = fmaxf(acc[ocr][0] + b, 0.f); v0.y = fmaxf(acc[ocr][1] + b, 0.f);
      v0.z = fmaxf(acc[ocr][2] + b, 0.f); v0.w = fmaxf(acc[ocr][3] + b, 0.f);
      v1.x = fmaxf(acc[ocr][4] + b, 0.f); v1.y = fmaxf(acc[ocr][5] + b, 0.f);
      v1.z = fmaxf(acc[ocr][6] + b, 0.f); v1.w = fmaxf(acc[ocr][7] + b, 0.f);
      *(float4*)&sBuf[base]     = v0;                // bank-uniform b128 writes
      *(float4*)&sBuf[base + 4] = v1;
    }
    __syncthreads();

    // conv2 partial: lane = oc2; wave handles local ic = wvu*4 + (0..3)
    #pragma unroll 1
    for (int icr = 0; icr < 4; icr++) {
      int icl = wvu * 4 + icr;
      int ic  = half * 16 + icl;
      const float* cbase = sBuf + icl * kCS;
      #pragma unroll 1
      for (int td = 0; td < 3; td++) {
        #pragma unroll
        for (int th = 0; th < 3; th++) {
          float wx, wy, wz;
          if (WPACK) {
            float4 w = ((const float4*)w2t4)[((ic * 9 + td * 3 + th) << 6) + oc2];
            wx = w.x; wy = w.y; wz = w.z;            // coalesced dwordx4
          } else {
            const float* wp = c2w + oc2 * 864 + ic * 27 + td * 9 + th * 3;
            wx = wp[0]; wy = wp[1]; wz = wp[2];
          }
          #pragma unroll
          for (int zo = 0; zo < 3; zo++) {
            #pragma unroll
            for (int yo = 0; yo < 3; yo++) {
              const float4* rp4 =
                  (const float4*)(cbase + (2 * zo + td) * kZS + (2 * yo + th) * 8);
              float4 r0 = rp4[0], r1 = rp4[1];       // broadcast b128, no conflict
              acc2[zo * 9 + yo * 3 + 0] += r0.x * wx + r0.y * wy + r0.z * wz;
              acc2[zo * 9 + yo * 3 + 1] += r0.z * wx + r0.w * wy + r1.x * wz;
              acc2[zo * 9 + yo * 3 + 2] += r1.x * wx + r1.y * wy + r1.z * wz;
            }
          }
        }
      }
    }
  }
  __syncthreads();
  // cross-wave reduce of conv2 partials: [wv][pos][oc] in [0, 6912)
  #pragma unroll
  for (int pos = 0; pos < 27; pos++)
    sBuf[(wvu * 27 + pos) * 64 + oc2] = acc2[pos];
  __syncthreads();
  float* sH = sBuf + kHOff;           // h[k], k = o*27 + pos
  for (int idx = t; idx < 1728; idx += 256) {
    int o = idx & 63, pos = idx >> 6;
    float v = sBuf[pos * 64 + o] + sBuf[(27 + pos) * 64 + o] +
              sBuf[(54 + pos) * 64 + o] + sBuf[(81 + pos) * 64 + o];
    sH[o * 27 + pos] = fmaxf(v + c2b[o], 0.f);
  }
  __syncthreads();

  // ---- fc1 (n = t) + fc2 + tanh ----
  float acc1 = 0.f;
  if (WPACK) {
    const float4* w4p = (const float4*)fw1;          // W1T4[k4][n]
    const float4* sH4 = (const float4*)sH;
    #pragma unroll 8
    for (int k4 = 0; k4 < 432; k4++) {
      float4 w  = w4p[k4 * 256 + t];
      float4 hv = sH4[k4];
      acc1 += w.x * hv.x + w.y * hv.y + w.z * hv.z + w.w * hv.w;
    }
  } else {
    const float* frow = fw1 + (size_t)t * 1728;
    #pragma unroll 8
    for (int k = 0; k < 1728; k++) acc1 += sH[k] * frow[k];
  }
  float h = fmaxf(acc1 + f1b[t], 0.f);
  sRed[t] = h * f2w[t];
  __syncthreads();
  for (int o = 128; o > 0; o >>= 1) {
    if (t < o) sRed[t] += sRed[t + o];
    __syncthreads();
  }
  float2 rk;
  rk.x = tanhf(sRed[0] + f2b[0]) * keep;
  rk.y = keep;
  __syncthreads();
  return rk;
}

// ---- pack f1w[n][k] -> W1T4[k4][n] ----
__global__ void dmr17_tr(const float* __restrict__ f1w, float* __restrict__ w1t4) {
  int k4 = blockIdx.x;                 // 0..431
  int n  = threadIdx.x;                // 0..255
  const float* s = f1w + (size_t)n * 1728 + k4 * 4;
  float4 w; w.x = s[0]; w.y = s[1]; w.z = s[2]; w.w = s[3];
  ((float4*)w1t4)[k4 * 256 + n] = w;
}

// ---- pack c2w[oc][ic][27] -> W2T4[(ic*9+td*3+th)][oc] = {w0,w1,w2,0} ----
__global__ void dmr17_tw2(const float* __restrict__ c2w, float* __restrict__ w2t4) {
  int gid = blockIdx.x * 256 + threadIdx.x;   // 72*256 = 18432 = 288*64
  int icth = gid >> 6, oc = gid & 63;
  const float* s = c2w + (size_t)oc * 864 + icth * 3;
  float4 w; w.x = s[0]; w.y = s[1]; w.z = s[2]; w.w = 0.f;
  ((float4*)w2t4)[gid] = w;
}

// ---- hot kernel (identifier-named): one patch per block, 4 blocks/CU ----
__global__ __launch_bounds__(256, 4)
void DMMRLoss_52621939310662_kernel(
    const float* __restrict__ src, const float* __restrict__ tgt,
    const float* __restrict__ c1w, const float* __restrict__ c1b,
    const float* __restrict__ c2w, const float* __restrict__ c2b,
    const float* __restrict__ w2t4,
    const float* __restrict__ w1t4, const float* __restrict__ f1b,
    const float* __restrict__ f2w, const float* __restrict__ f2b,
    float* __restrict__ pr, float* __restrict__ pk) {
  __shared__ float sBuf[8832];
  __shared__ float sRed[256];
  int t = threadIdx.x;
  float2 rk = dmr17_patch<true>(blockIdx.x, t, src, tgt, c1w, c1b, c2w, c2b,
                                w2t4, w1t4, f1b, f2w, f2b, sBuf, sRed);
  if (t == 0) { pr[blockIdx.x] = rk.x; pk[blockIdx.x] = rk.y; }
}

// ---- raw hot fallback (ws too small for packs) ----
__global__ __launch_bounds__(256, 4)
void dmr17_hot_raw(const float* __restrict__ src, const float* __restrict__ tgt,
                   const float* __restrict__ c1w, const float* __restrict__ c1b,
                   const float* __restrict__ c2w, const float* __restrict__ c2b,
                   const float* __restrict__ f1w, const float* __restrict__ f1b,
                   const float* __restrict__ f2w, const float* __restrict__ f2b,
                   float* __restrict__ pr, float* __restrict__ pk) {
  __shared__ float sBuf[8832];
  __shared__ float sRed[256];
  int t = threadIdx.x;
  float2 rk = dmr17_patch<false>(blockIdx.x, t, src, tgt, c1w, c1b, c2w, c2b,
                                 nullptr, f1w, f1b, f2w, f2b, sBuf, sRed);
  if (t == 0) { pr[blockIdx.x] = rk.x; pk[blockIdx.x] = rk.y; }
}

// ---- final reduce -> float32 scalar ----
__global__ void dmr17_reduce(const float* __restrict__ pr, const float* __restrict__ pk,
                             float* __restrict__ out) {
  __shared__ float s1[256], s2[256];
  int t = threadIdx.x;
  float a = 0.f, b = 0.f;
  for (int p = t; p < 2197; p += 256) { a += pr[p]; b += pk[p]; }
  s1[t] = a; s2[t] = b;
  __syncthreads();
  for (int o = 128; o > 0; o >>= 1) {
    if (t < o) { s1[t] += s1[t + o]; s2[t] += s2[t + o]; }
    __syncthreads();
  }
  if (t == 0) out[0] = s1[0] / s2[0];
}

// ---- ws-free fallback: single block does everything ----
__global__ __launch_bounds__(256, 4)
void dmr17_solo(const float* __restrict__ src, const float* __restrict__ tgt,
                const float* __restrict__ c1w, const float* __restrict__ c1b,
                const float* __restrict__ c2w, const float* __restrict__ c2b,
                const float* __restrict__ f1w, const float* __restrict__ f1b,
                const float* __restrict__ f2w, const float* __restrict__ f2b,
                float* __restrict__ out) {
  __shared__ float sBuf[8832];
  __shared__ float sRed[256];
  __shared__ float sAcc[2];
  int t = threadIdx.x;
  if (t == 0) { sAcc[0] = 0.f; sAcc[1] = 0.f; }
  for (int p = 0; p < 2197; p++) {
    __syncthreads();
    float2 rk = dmr17_patch<false>(p, t, src, tgt, c1w, c1b, c2w, c2b,
                                   nullptr, f1w, f1b, f2w, f2b, sBuf, sRed);
    if (t == 0) { sAcc[0] += rk.x; sAcc[1] += rk.y; }
  }
  __syncthreads();
  if (t == 0) out[0] = sAcc[0] / sAcc[1];
}

extern "C" void kernel_launch(void* const* d_in, const int* in_sizes, int n_in,
                              void* d_out, int out_size, void* d_ws, size_t ws_size,
                              hipStream_t stream) {
  const float* src = (const float*)d_in[0];   // source = moving
  const float* tgt = (const float*)d_in[1];   // target = fixed
  const float* c1w = (const float*)d_in[2];
  const float* c1b = (const float*)d_in[3];
  const float* c2w = (const float*)d_in[4];
  const float* c2b = (const float*)d_in[5];
  const float* f1w = (const float*)d_in[6];
  const float* f1b = (const float*)d_in[7];
  const float* f2w = (const float*)d_in[8];
  const float* f2b = (const float*)d_in[9];
  float* out = (float*)d_out;

  const size_t nW1T = 442368;                 // 1728*256
  const size_t nW2T = 73728;                  // 288*64*4
  const size_t nPK  = 2 * 2197;
  if (d_ws && ws_size >= (nW1T + nW2T + nPK) * sizeof(float)) {
    float* w1t4 = (float*)d_ws;               // 16B-aligned at ws+0
    float* w2t4 = w1t4 + nW1T;                // still 16B-aligned
    float* pr   = w2t4 + nW2T;
    float* pk   = pr + 2197;
    dmr17_tr<<<432, 256, 0, stream>>>(f1w, w1t4);
    dmr17_tw2<<<72, 256, 0, stream>>>(c2w, w2t4);
    DMMRLoss_52621939310662_kernel<<<2197, 256, 0, stream>>>(
        src, tgt, c1w, c1b, c2w, c2b, w2t4, w1t4, f1b, f2w, f2b, pr, pk);
    dmr17_reduce<<<1, 256, 0, stream>>>(pr, pk, out);
  } else if (d_ws && ws_size >= nPK * sizeof(float)) {
    float* pr = (float*)d_ws;
    float* pk = pr + 2197;
    dmr17_hot_raw<<<2197, 256, 0, stream>>>(
        src, tgt, c1w, c1b, c2w, c2b, f1w, f1b, f2w, f2b, pr, pk);
    dmr17_reduce<<<1, 256, 0, stream>>>(pr, pk, out);
  } else {
    dmr17_solo<<<1, 256, 0, stream>>>(
        src, tgt, c1w, c1b, c2w, c2b, f1w, f1b, f2w, f2b, out);
  }
}

// Round 18
// 461.559 us; speedup vs baseline: 2.1832x; 2.1832x over previous
//
#include <hip/hip_runtime.h>

// DMMRLoss_52621939310662 — round 18: r16 base + low-pressure r17 deltas.
// r17 regressed (438->1008us): full th-unroll in conv2 overflowed the 64-VGPR
// budget -> 2.7 GB spill writes. This round re-applies only the issue-slot
// cuts that don't raise peak live registers:
//   - conv2 activation reads as broadcast ds_read_b128 (th loop stays rolled)
//   - conv2 weights pre-packed W2T4[(ic,td,th)][oc] float4 (coalesced)
//   - conv1-out writes as b128 (CS=552, ZS=68: 16B-aligned rows)
// Spill canary: WRITE_SIZE must stay ~KB-scale.

static constexpr int kPS = 433;    // staging plane stride (4-way floor)
static constexpr int kRS = 25;     // staging row stride
static constexpr int kCS = 552;    // conv1-out channel stride (mult 4)
static constexpr int kZS = 68;     // conv1-out z stride (mult 4)
static constexpr int kHOff = 6912; // h[k] region after partials

template <bool WPACK>
static __device__ __forceinline__ float2 dmr18_patch(
    int p, int t,
    const float* __restrict__ src, const float* __restrict__ tgt,
    const float* __restrict__ c1w, const float* __restrict__ c1b,
    const float* __restrict__ c2w, const float* __restrict__ c2b,
    const float* __restrict__ w2t4,
    const float* __restrict__ fw1, const float* __restrict__ f1b,
    const float* __restrict__ f2w, const float* __restrict__ f2b,
    float* __restrict__ sBuf, float* __restrict__ sRed) {
  int pd = p / 169; int rem = p - pd * 169; int phh = rem / 13; int pww = rem - phh * 13;
  int z0 = pd * 17, y0 = phh * 17, x0 = pww * 17;

  int wv  = t >> 6;                   // wave 0..3
  int od  = (t >> 3) & 7, oh = t & 7;
  int oc2 = t & 63;

  // ---- stage tgt patch + count zeros ----
  float cnt = 0.f;
  for (int idx = t; idx < 4913; idx += 256) {
    int a = idx / 289; int r2 = idx - a * 289; int b = r2 / 17; int c = r2 - b * 17;
    float v = tgt[((size_t)(z0 + a) * 222 + (y0 + b)) * 222 + (x0 + c)];
    sBuf[a * kPS + b * kRS + c] = v;
    if (v == 0.0f) cnt += 1.f;
  }
  sRed[t] = cnt;
  __syncthreads();
  for (int o = 128; o > 0; o >>= 1) {
    if (t < o) sRed[t] += sRed[t + o];
    __syncthreads();
  }
  float keep = (sRed[0] / 4913.0f <= 0.5f) ? 1.0f : 0.0f;
  __syncthreads();

  float acc2[27];
  #pragma unroll
  for (int i = 0; i < 27; i++) acc2[i] = 0.f;

  #pragma unroll 1
  for (int half = 0; half < 2; half++) {
    float acc[4][8];
    #pragma unroll
    for (int i = 0; i < 4; i++)
      #pragma unroll
      for (int j = 0; j < 8; j++) acc[i][j] = 0.f;

    #pragma unroll 1
    for (int ic = 0; ic < 2; ic++) {
      if (half + ic > 0) {            // restage: src (ic1) or tgt (half1/ic0)
        const float* vol = ic ? src : tgt;
        __syncthreads();
        for (int idx = t; idx < 4913; idx += 256) {
          int a = idx / 289; int r2 = idx - a * 289; int b = r2 / 17; int c = r2 - b * 17;
          sBuf[a * kPS + b * kRS + c] =
              vol[((size_t)(z0 + a) * 222 + (y0 + b)) * 222 + (x0 + c)];
        }
        __syncthreads();
      }
      #pragma unroll 1
      for (int td = 0; td < 3; td++) {
        #pragma unroll 1
        for (int th = 0; th < 3; th++) {
          int rbase = (2 * od + td) * kPS + (2 * oh + th) * kRS;
          float a[17];
          #pragma unroll
          for (int x = 0; x < 17; x++) a[x] = sBuf[rbase + x];
          #pragma unroll
          for (int ocr = 0; ocr < 4; ocr++) {
            int oc = half * 16 + wv * 4 + ocr;
            const float* wp = c1w + oc * 54 + ic * 27 + td * 9 + th * 3;
            float w0 = wp[0], w1 = wp[1], w2 = wp[2];
            #pragma unroll
            for (int ow = 0; ow < 8; ow++)
              acc[ocr][ow] += a[2 * ow] * w0 + a[2 * ow + 1] * w1 + a[2 * ow + 2] * w2;
          }
        }
      }
    }
    __syncthreads();                  // conv1 reads of staged patch done
    #pragma unroll
    for (int ocr = 0; ocr < 4; ocr++) {
      int lo = wv * 4 + ocr;
      float b = c1b[half * 16 + lo];
      int base = lo * kCS + od * kZS + oh * 8;       // 16B-aligned
      float4 v0, v1;
      v0.x = fmaxf(acc[ocr][0] + b, 0.f); v0.y = fmaxf(acc[ocr][1] + b, 0.f);
      v0.z = fmaxf(acc[ocr][2] + b, 0.f); v0.w = fmaxf(acc[ocr][3] + b, 0.f);
      v1.x = fmaxf(acc[ocr][4] + b, 0.f); v1.y = fmaxf(acc[ocr][5] + b, 0.f);
      v1.z = fmaxf(acc[ocr][6] + b, 0.f); v1.w = fmaxf(acc[ocr][7] + b, 0.f);
      *(float4*)&sBuf[base]     = v0;
      *(float4*)&sBuf[base + 4] = v1;
    }
    __syncthreads();

    // conv2 partial: lane = oc2; wave handles local ic = wv*4 + (0..3).
    // All loops except zo/yo/xo stay rolled -> low register pressure.
    #pragma unroll 1
    for (int icr = 0; icr < 4; icr++) {
      int icl = wv * 4 + icr;
      int ic  = half * 16 + icl;
      const float* cbase = sBuf + icl * kCS;
      #pragma unroll 1
      for (int td = 0; td < 3; td++) {
        #pragma unroll 1
        for (int th = 0; th < 3; th++) {
          float wx, wy, wz;
          if (WPACK) {
            float4 w = ((const float4*)w2t4)[((ic * 9 + td * 3 + th) << 6) + oc2];
            wx = w.x; wy = w.y; wz = w.z;            // coalesced dwordx4
          } else {
            const float* wp = c2w + oc2 * 864 + ic * 27 + td * 9 + th * 3;
            wx = wp[0]; wy = wp[1]; wz = wp[2];
          }
          #pragma unroll
          for (int zo = 0; zo < 3; zo++) {
            #pragma unroll
            for (int yo = 0; yo < 3; yo++) {
              const float4* rp4 =
                  (const float4*)(cbase + (2 * zo + td) * kZS + (2 * yo + th) * 8);
              float4 r0 = rp4[0], r1 = rp4[1];       // broadcast b128
              acc2[zo * 9 + yo * 3 + 0] += r0.x * wx + r0.y * wy + r0.z * wz;
              acc2[zo * 9 + yo * 3 + 1] += r0.z * wx + r0.w * wy + r1.x * wz;
              acc2[zo * 9 + yo * 3 + 2] += r1.x * wx + r1.y * wy + r1.z * wz;
            }
          }
        }
      }
    }
  }
  __syncthreads();
  // cross-wave reduce of conv2 partials: [wv][pos][oc] in [0, 6912)
  #pragma unroll
  for (int pos = 0; pos < 27; pos++)
    sBuf[(wv * 27 + pos) * 64 + oc2] = acc2[pos];
  __syncthreads();
  float* sH = sBuf + kHOff;           // h[k], k = o*27 + pos
  for (int idx = t; idx < 1728; idx += 256) {
    int o = idx & 63, pos = idx >> 6;
    float v = sBuf[pos * 64 + o] + sBuf[(27 + pos) * 64 + o] +
              sBuf[(54 + pos) * 64 + o] + sBuf[(81 + pos) * 64 + o];
    sH[o * 27 + pos] = fmaxf(v + c2b[o], 0.f);
  }
  __syncthreads();

  // ---- fc1 (n = t) + fc2 + tanh ----
  float acc1 = 0.f;
  if (WPACK) {
    const float4* w4p = (const float4*)fw1;          // W1T4[k4][n]
    const float4* sH4 = (const float4*)sH;
    #pragma unroll 8
    for (int k4 = 0; k4 < 432; k4++) {
      float4 w  = w4p[k4 * 256 + t];
      float4 hv = sH4[k4];
      acc1 += w.x * hv.x + w.y * hv.y + w.z * hv.z + w.w * hv.w;
    }
  } else {
    const float* frow = fw1 + (size_t)t * 1728;
    #pragma unroll 8
    for (int k = 0; k < 1728; k++) acc1 += sH[k] * frow[k];
  }
  float h = fmaxf(acc1 + f1b[t], 0.f);
  sRed[t] = h * f2w[t];
  __syncthreads();
  for (int o = 128; o > 0; o >>= 1) {
    if (t < o) sRed[t] += sRed[t + o];
    __syncthreads();
  }
  float2 rk;
  rk.x = tanhf(sRed[0] + f2b[0]) * keep;
  rk.y = keep;
  __syncthreads();
  return rk;
}

// ---- pack f1w[n][k] -> W1T4[k4][n] ----
__global__ void dmr18_tr(const float* __restrict__ f1w, float* __restrict__ w1t4) {
  int k4 = blockIdx.x;                 // 0..431
  int n  = threadIdx.x;                // 0..255
  const float* s = f1w + (size_t)n * 1728 + k4 * 4;
  float4 w; w.x = s[0]; w.y = s[1]; w.z = s[2]; w.w = s[3];
  ((float4*)w1t4)[k4 * 256 + n] = w;
}

// ---- pack c2w[oc][ic][27] -> W2T4[(ic*9+td*3+th)][oc] = {w0,w1,w2,0} ----
__global__ void dmr18_tw2(const float* __restrict__ c2w, float* __restrict__ w2t4) {
  int gid = blockIdx.x * 256 + threadIdx.x;   // 72*256 = 18432 = 288*64
  int icth = gid >> 6, oc = gid & 63;
  const float* s = c2w + (size_t)oc * 864 + icth * 3;
  float4 w; w.x = s[0]; w.y = s[1]; w.z = s[2]; w.w = 0.f;
  ((float4*)w2t4)[gid] = w;
}

// ---- hot kernel (identifier-named): one patch per block, 4 blocks/CU ----
__global__ __launch_bounds__(256, 4)
void DMMRLoss_52621939310662_kernel(
    const float* __restrict__ src, const float* __restrict__ tgt,
    const float* __restrict__ c1w, const float* __restrict__ c1b,
    const float* __restrict__ c2w, const float* __restrict__ c2b,
    const float* __restrict__ w2t4,
    const float* __restrict__ w1t4, const float* __restrict__ f1b,
    const float* __restrict__ f2w, const float* __restrict__ f2b,
    float* __restrict__ pr, float* __restrict__ pk) {
  __shared__ float sBuf[8832];
  __shared__ float sRed[256];
  int t = threadIdx.x;
  float2 rk = dmr18_patch<true>(blockIdx.x, t, src, tgt, c1w, c1b, c2w, c2b,
                                w2t4, w1t4, f1b, f2w, f2b, sBuf, sRed);
  if (t == 0) { pr[blockIdx.x] = rk.x; pk[blockIdx.x] = rk.y; }
}

// ---- raw hot fallback (ws too small for packs) ----
__global__ __launch_bounds__(256, 4)
void dmr18_hot_raw(const float* __restrict__ src, const float* __restrict__ tgt,
                   const float* __restrict__ c1w, const float* __restrict__ c1b,
                   const float* __restrict__ c2w, const float* __restrict__ c2b,
                   const float* __restrict__ f1w, const float* __restrict__ f1b,
                   const float* __restrict__ f2w, const float* __restrict__ f2b,
                   float* __restrict__ pr, float* __restrict__ pk) {
  __shared__ float sBuf[8832];
  __shared__ float sRed[256];
  int t = threadIdx.x;
  float2 rk = dmr18_patch<false>(blockIdx.x, t, src, tgt, c1w, c1b, c2w, c2b,
                                 nullptr, f1w, f1b, f2w, f2b, sBuf, sRed);
  if (t == 0) { pr[blockIdx.x] = rk.x; pk[blockIdx.x] = rk.y; }
}

// ---- final reduce -> float32 scalar ----
__global__ void dmr18_reduce(const float* __restrict__ pr, const float* __restrict__ pk,
                             float* __restrict__ out) {
  __shared__ float s1[256], s2[256];
  int t = threadIdx.x;
  float a = 0.f, b = 0.f;
  for (int p = t; p < 2197; p += 256) { a += pr[p]; b += pk[p]; }
  s1[t] = a; s2[t] = b;
  __syncthreads();
  for (int o = 128; o > 0; o >>= 1) {
    if (t < o) { s1[t] += s1[t + o]; s2[t] += s2[t + o]; }
    __syncthreads();
  }
  if (t == 0) out[0] = s1[0] / s2[0];
}

// ---- ws-free fallback: single block does everything ----
__global__ __launch_bounds__(256, 4)
void dmr18_solo(const float* __restrict__ src, const float* __restrict__ tgt,
                const float* __restrict__ c1w, const float* __restrict__ c1b,
                const float* __restrict__ c2w, const float* __restrict__ c2b,
                const float* __restrict__ f1w, const float* __restrict__ f1b,
                const float* __restrict__ f2w, const float* __restrict__ f2b,
                float* __restrict__ out) {
  __shared__ float sBuf[8832];
  __shared__ float sRed[256];
  __shared__ float sAcc[2];
  int t = threadIdx.x;
  if (t == 0) { sAcc[0] = 0.f; sAcc[1] = 0.f; }
  for (int p = 0; p < 2197; p++) {
    __syncthreads();
    float2 rk = dmr18_patch<false>(p, t, src, tgt, c1w, c1b, c2w, c2b,
                                   nullptr, f1w, f1b, f2w, f2b, sBuf, sRed);
    if (t == 0) { sAcc[0] += rk.x; sAcc[1] += rk.y; }
  }
  __syncthreads();
  if (t == 0) out[0] = sAcc[0] / sAcc[1];
}

extern "C" void kernel_launch(void* const* d_in, const int* in_sizes, int n_in,
                              void* d_out, int out_size, void* d_ws, size_t ws_size,
                              hipStream_t stream) {
  const float* src = (const float*)d_in[0];   // source = moving
  const float* tgt = (const float*)d_in[1];   // target = fixed
  const float* c1w = (const float*)d_in[2];
  const float* c1b = (const float*)d_in[3];
  const float* c2w = (const float*)d_in[4];
  const float* c2b = (const float*)d_in[5];
  const float* f1w = (const float*)d_in[6];
  const float* f1b = (const float*)d_in[7];
  const float* f2w = (const float*)d_in[8];
  const float* f2b = (const float*)d_in[9];
  float* out = (float*)d_out;

  const size_t nW1T = 442368;                 // 1728*256
  const size_t nW2T = 73728;                  // 288*64*4
  const size_t nPK  = 2 * 2197;
  if (d_ws && ws_size >= (nW1T + nW2T + nPK) * sizeof(float)) {
    float* w1t4 = (float*)d_ws;               // 16B-aligned at ws+0
    float* w2t4 = w1t4 + nW1T;                // still 16B-aligned
    float* pr   = w2t4 + nW2T;
    float* pk   = pr + 2197;
    dmr18_tr<<<432, 256, 0, stream>>>(f1w, w1t4);
    dmr18_tw2<<<72, 256, 0, stream>>>(c2w, w2t4);
    DMMRLoss_52621939310662_kernel<<<2197, 256, 0, stream>>>(
        src, tgt, c1w, c1b, c2w, c2b, w2t4, w1t4, f1b, f2w, f2b, pr, pk);
    dmr18_reduce<<<1, 256, 0, stream>>>(pr, pk, out);
  } else if (d_ws && ws_size >= nPK * sizeof(float)) {
    float* pr = (float*)d_ws;
    float* pk = pr + 2197;
    dmr18_hot_raw<<<2197, 256, 0, stream>>>(
        src, tgt, c1w, c1b, c2w, c2b, f1w, f1b, f2w, f2b, pr, pk);
    dmr18_reduce<<<1, 256, 0, stream>>>(pr, pk, out);
  } else {
    dmr18_solo<<<1, 256, 0, stream>>>(
        src, tgt, c1w, c1b, c2w, c2b, f1w, f1b, f2w, f2b, out);
  }
}